// Round 2
// baseline (294.714 us; speedup 1.0000x reference)
//
#include <hip/hip_runtime.h>

#define IN_F 512
#define OUT_F 1024
#define K_ACTIVE 11  // ceil(0.01 * 1024) serial MP steps
#define K_IN 6       // ceil(0.01 * 512) kwta winners

// 32x32 LDS-tiled transpose: w [OUT_F][IN_F] -> wT [IN_F][OUT_F]
__global__ __launch_bounds__(256) void transpose_w_kernel(const float* __restrict__ w,
                                                          float* __restrict__ wT) {
    __shared__ float tile[32][33];
    const int tx = threadIdx.x & 31;
    const int ty = threadIdx.x >> 5;  // 0..7
    const int i0 = blockIdx.x * 32;   // IN_F tile base
    const int j0 = blockIdx.y * 32;   // OUT_F tile base
#pragma unroll
    for (int k = 0; k < 4; ++k)
        tile[ty + 8 * k][tx] = w[(size_t)(j0 + ty + 8 * k) * IN_F + (i0 + tx)];
    __syncthreads();
#pragma unroll
    for (int k = 0; k < 4; ++k)
        wT[(size_t)(i0 + ty + 8 * k) * OUT_F + (j0 + tx)] = tile[tx][ty + 8 * k];
}

// One wave per row. Lane layout: j = lane*16 + q (OUT), i = lane*8 + p (IN)
// -> every per-lane slot group is 64B contiguous => dwordx4 loads.
// All decision math in fp64 (exactness bought absmax=0 in R1); reductions are
// value-only fp64 butterflies + ballot/ffs/readlane index location.
template <bool USE_T>
__global__ __launch_bounds__(64, 4) void bmp_kernel(const float* __restrict__ x,
                                                    const float* __restrict__ w,
                                                    const float* __restrict__ wT,
                                                    float* __restrict__ out, int rows) {
    __shared__ unsigned short act[IN_F];
    const int lane = threadIdx.x;
    const int row = blockIdx.x;
    if (row >= rows) return;

    // ---- compacted active list of x row (binary SDR, ~51 of 512) ----
    const float* xrow = x + (size_t)row * IN_F;
    int cnt = 0;
#pragma unroll
    for (int c = 0; c < IN_F / 64; ++c) {
        bool pbit = xrow[c * 64 + lane] != 0.0f;
        unsigned long long m = __ballot(pbit);
        int pre = __popcll(m & ((1ull << lane) - 1ull));
        if (pbit) act[cnt + pre] = (unsigned short)(c * 64 + lane);
        cnt += __popcll(m);
    }
    __syncthreads();
    // active indices live in 2 VGPRs; fetched per-k via readlane (no LDS in loop)
    const int a0i = act[lane];
    const int a1i = act[64 + lane];

    // ---- xw2[j] = 2 * sum_{i active} W[j][i]  (fp64 accumulators) ----
    double acc[16];
#pragma unroll
    for (int q = 0; q < 16; ++q) acc[q] = 0.0;

    auto gather_add = [&](int iu) {
        if constexpr (USE_T) {
            const float* rp = wT + ((size_t)iu << 10) + lane * 16;
            const float4 b0 = *(const float4*)(rp);
            const float4 b1 = *(const float4*)(rp + 4);
            const float4 b2 = *(const float4*)(rp + 8);
            const float4 b3 = *(const float4*)(rp + 12);
            acc[0] += (double)b0.x;  acc[1] += (double)b0.y;
            acc[2] += (double)b0.z;  acc[3] += (double)b0.w;
            acc[4] += (double)b1.x;  acc[5] += (double)b1.y;
            acc[6] += (double)b1.z;  acc[7] += (double)b1.w;
            acc[8] += (double)b2.x;  acc[9] += (double)b2.y;
            acc[10] += (double)b2.z; acc[11] += (double)b2.w;
            acc[12] += (double)b3.x; acc[13] += (double)b3.y;
            acc[14] += (double)b3.z; acc[15] += (double)b3.w;
        } else {
#pragma unroll
            for (int q = 0; q < 16; ++q)
                acc[q] += (double)w[(size_t)(lane * 16 + q) * IN_F + iu];
        }
    };

    {
        int k = 0;
        const int n0 = cnt < 64 ? cnt : 64;
        for (; k < n0; ++k) gather_add(__builtin_amdgcn_readfirstlane(__shfl(a0i, k)));
        const int n1 = cnt < 128 ? cnt : 128;
        for (; k < n1; ++k) gather_add(__builtin_amdgcn_readfirstlane(__shfl(a1i, k - 64)));
        for (; k < cnt; ++k) gather_add((int)act[k]);  // cnt>128 never happens in practice
    }
#pragma unroll
    for (int q = 0; q < 16; ++q) acc[q] *= 2.0;

    // v = encoded @ W, grown one W-row per step (fp64)
    double vd[8];
#pragma unroll
    for (int p = 0; p < 8; ++p) vd[p] = 0.0;

    unsigned enc = 0, sel = 0;           // per-lane slot masks (q over OUT, p over IN)
    int xr0 = 0, xr1 = 0, xr2 = 0, xr3 = 0, xr4 = 0, xr5 = 0;  // wave-uniform

    for (int t = 0; t < K_ACTIVE; ++t) {
        // ---- argmax of residual over non-encoded j (lambd >> |dot| => exclusion) ----
        double lbv = -1.0e300;
        int lbq = 0;
        if (t == 0) {
#pragma unroll
            for (int q = 0; q < 16; ++q)
                if (acc[q] > lbv) { lbv = acc[q]; lbq = q; }
        } else if constexpr (USE_T) {
            const float* p0 = wT + ((size_t)xr0 << 10) + lane * 16;
            const float* p1 = wT + ((size_t)xr1 << 10) + lane * 16;
            const float* p2 = wT + ((size_t)xr2 << 10) + lane * 16;
            const float* p3 = wT + ((size_t)xr3 << 10) + lane * 16;
            const float* p4 = wT + ((size_t)xr4 << 10) + lane * 16;
            const float* p5 = wT + ((size_t)xr5 << 10) + lane * 16;
#pragma unroll
            for (int c = 0; c < 4; ++c) {
                const float4 f0 = *(const float4*)(p0 + 4 * c);
                const float4 f1 = *(const float4*)(p1 + 4 * c);
                const float4 f2 = *(const float4*)(p2 + 4 * c);
                const float4 f3 = *(const float4*)(p3 + 4 * c);
                const float4 f4 = *(const float4*)(p4 + 4 * c);
                const float4 f5 = *(const float4*)(p5 + 4 * c);
#define RES_E(EO, CMP)                                                              \
    do {                                                                            \
        const int q = 4 * c + EO;                                                   \
        if (!(enc & (1u << q))) {                                                   \
            double rr = acc[q] - (double)f0.CMP - (double)f1.CMP - (double)f2.CMP   \
                        - (double)f3.CMP - (double)f4.CMP - (double)f5.CMP;         \
            if (rr > lbv) { lbv = rr; lbq = q; }                                    \
        }                                                                           \
    } while (0)
                RES_E(0, x); RES_E(1, y); RES_E(2, z); RES_E(3, w);
#undef RES_E
            }
        } else {
#pragma unroll
            for (int q = 0; q < 16; ++q) {
                if (enc & (1u << q)) continue;
                const size_t jb = (size_t)(lane * 16 + q) * IN_F;
                double rr = acc[q] - (double)w[jb + xr0] - (double)w[jb + xr1]
                            - (double)w[jb + xr2] - (double)w[jb + xr3]
                            - (double)w[jb + xr4] - (double)w[jb + xr5];
                if (rr > lbv) { lbv = rr; lbq = q; }
            }
        }

        // value-only butterfly max, then ballot locates winner (lowest index wins ties)
        double gbv = lbv;
#pragma unroll
        for (int off = 32; off; off >>= 1) {
            double o = __shfl_xor(gbv, off);
            gbv = (o > gbv) ? o : gbv;
        }
        const unsigned long long mk = __ballot(lbv == gbv);
        const int L = __ffsll(mk) - 1;
        const int bq = __builtin_amdgcn_readfirstlane(__shfl(lbq, L));
        const int bestj = (L << 4) + bq;  // j = lane*16 + q, lane-major => ffs = lowest j
        if (lane == L) enc |= (1u << bq);

        // ---- v += W[bestj][:] ----
        const float* wr = w + ((size_t)bestj << 9) + lane * 8;
        const float4 w0 = *(const float4*)(wr);
        const float4 w1 = *(const float4*)(wr + 4);
        vd[0] += (double)w0.x; vd[1] += (double)w0.y;
        vd[2] += (double)w0.z; vd[3] += (double)w0.w;
        vd[4] += (double)w1.x; vd[5] += (double)w1.y;
        vd[6] += (double)w1.z; vd[7] += (double)w1.w;

        // ---- kwta: top-6 set of v, lowest-index tie-break ----
        sel = 0;
        int nxr[6];
#pragma unroll
        for (int s = 0; s < K_IN; ++s) {
            double kv = -1.0e300;
            int kp = 0;
#pragma unroll
            for (int p = 0; p < 8; ++p)
                if (!(sel & (1u << p)) && vd[p] > kv) { kv = vd[p]; kp = p; }
            double g = kv;
#pragma unroll
            for (int off = 32; off; off >>= 1) {
                double o = __shfl_xor(g, off);
                g = (o > g) ? o : g;
            }
            const unsigned long long m2 = __ballot(kv == g);
            const int L2 = __ffsll(m2) - 1;
            const int p2 = __builtin_amdgcn_readfirstlane(__shfl(kp, L2));
            if (lane == L2) sel |= 1u << p2;
            nxr[s] = (L2 << 3) + p2;
        }
        xr0 = nxr[0]; xr1 = nxr[1]; xr2 = nxr[2];
        xr3 = nxr[3]; xr4 = nxr[4]; xr5 = nxr[5];
    }

    // ---- outputs: encoded [rows][OUT_F] then xr [rows][IN_F], float4 stores ----
    float* oe = out + (size_t)row * OUT_F + lane * 16;
#pragma unroll
    for (int c = 0; c < 4; ++c) {
        float4 v;
        v.x = ((enc >> (4 * c + 0)) & 1u) ? 1.0f : 0.0f;
        v.y = ((enc >> (4 * c + 1)) & 1u) ? 1.0f : 0.0f;
        v.z = ((enc >> (4 * c + 2)) & 1u) ? 1.0f : 0.0f;
        v.w = ((enc >> (4 * c + 3)) & 1u) ? 1.0f : 0.0f;
        *(float4*)(oe + 4 * c) = v;
    }
    float* ox = out + (size_t)rows * OUT_F + (size_t)row * IN_F + lane * 8;
    float4 u0, u1;
    u0.x = (sel & 1u) ? 1.0f : 0.0f;        u0.y = ((sel >> 1) & 1u) ? 1.0f : 0.0f;
    u0.z = ((sel >> 2) & 1u) ? 1.0f : 0.0f; u0.w = ((sel >> 3) & 1u) ? 1.0f : 0.0f;
    u1.x = ((sel >> 4) & 1u) ? 1.0f : 0.0f; u1.y = ((sel >> 5) & 1u) ? 1.0f : 0.0f;
    u1.z = ((sel >> 6) & 1u) ? 1.0f : 0.0f; u1.w = ((sel >> 7) & 1u) ? 1.0f : 0.0f;
    *(float4*)(ox) = u0;
    *(float4*)(ox + 4) = u1;
}

extern "C" void kernel_launch(void* const* d_in, const int* in_sizes, int n_in,
                              void* d_out, int out_size, void* d_ws, size_t ws_size,
                              hipStream_t stream) {
    const float* x = (const float*)d_in[0];
    const float* w = (const float*)d_in[1];
    float* out = (float*)d_out;
    const int rows = in_sizes[0] / IN_F;  // 4096

    const size_t wt_bytes = (size_t)IN_F * OUT_F * sizeof(float);
    if (ws_size >= wt_bytes && d_ws != nullptr) {
        float* wT = (float*)d_ws;
        transpose_w_kernel<<<dim3(IN_F / 32, OUT_F / 32), 256, 0, stream>>>(w, wT);
        bmp_kernel<true><<<rows, 64, 0, stream>>>(x, w, wT, out, rows);
    } else {
        bmp_kernel<false><<<rows, 64, 0, stream>>>(x, w, nullptr, out, rows);
    }
}

// Round 3
// 190.929 us; speedup vs baseline: 1.5436x; 1.5436x over previous
//
#include <hip/hip_runtime.h>

#define IN_F 512
#define OUT_F 1024
#define K_ACTIVE 11  // ceil(0.01 * 1024) serial MP steps
#define K_IN 6       // ceil(0.01 * 512) kwta winners

// 32x32 LDS-tiled transpose: w [OUT_F][IN_F] -> wT [IN_F][OUT_F]
__global__ __launch_bounds__(256) void transpose_w_kernel(const float* __restrict__ w,
                                                          float* __restrict__ wT) {
    __shared__ float tile[32][33];
    const int tx = threadIdx.x & 31;
    const int ty = threadIdx.x >> 5;  // 0..7
    const int i0 = blockIdx.x * 32;   // IN_F tile base
    const int j0 = blockIdx.y * 32;   // OUT_F tile base
#pragma unroll
    for (int k = 0; k < 4; ++k)
        tile[ty + 8 * k][tx] = w[(size_t)(j0 + ty + 8 * k) * IN_F + (i0 + tx)];
    __syncthreads();
#pragma unroll
    for (int k = 0; k < 4; ++k)
        wT[(size_t)(i0 + ty + 8 * k) * OUT_F + (j0 + tx)] = tile[tx][ty + 8 * k];
}

// ---- order-preserving fp64 -> u64 key, low bits carry reversed index ----
// max(key) == max value; ties -> lowest index. Drops 10 mantissa bits (2^-42 rel).
__device__ __forceinline__ unsigned long long pack_key(double v, unsigned rev,
                                                       unsigned long long mask) {
    unsigned long long b = (unsigned long long)__double_as_longlong(v);
    unsigned long long m =
        (unsigned long long)((long long)b >> 63) | 0x8000000000000000ull;
    unsigned long long u = b ^ m;  // monotonic total order
    return (u & ~mask) | (unsigned long long)rev;
}

// ---- wave-wide u64 max via DPP (VALU-speed, no LDS): result uniform ----
template <int C>
__device__ __forceinline__ unsigned long long dppmax(unsigned long long k) {
    unsigned lo = (unsigned)__builtin_amdgcn_update_dpp(0, (int)(unsigned)k, C, 0xF, 0xF, true);
    unsigned hi = (unsigned)__builtin_amdgcn_update_dpp(0, (int)(unsigned)(k >> 32), C, 0xF, 0xF, true);
    unsigned long long o = ((unsigned long long)hi << 32) | lo;
    return o > k ? o : k;
}

__device__ __forceinline__ unsigned long long wave_max_u64(unsigned long long k) {
    k = dppmax<0x111>(k);  // row_shr:1
    k = dppmax<0x112>(k);  // row_shr:2
    k = dppmax<0x114>(k);  // row_shr:4
    k = dppmax<0x118>(k);  // row_shr:8
    k = dppmax<0x142>(k);  // row_bcast:15
    k = dppmax<0x143>(k);  // row_bcast:31  -> lane 63 has wave max
    unsigned glo = (unsigned)__builtin_amdgcn_readlane((int)(unsigned)k, 63);
    unsigned ghi = (unsigned)__builtin_amdgcn_readlane((int)(unsigned)(k >> 32), 63);
    return ((unsigned long long)ghi << 32) | glo;
}

// r[s] += sgn * wT[i][slot s], slot s=4c+e <-> j = c*256 + lane*4 + e.
// USE_T path: 4 float4 loads, each 64 lanes x 16B = 1KB contiguous (coalesced).
template <bool USE_T>
__device__ __forceinline__ void wt_row_axpy(double* r, const float* __restrict__ wT,
                                            const float* __restrict__ w, int i,
                                            double sgn, int lane) {
    if constexpr (USE_T) {
        const float* rp = wT + ((size_t)i << 10) + (lane << 2);
#pragma unroll
        for (int c = 0; c < 4; ++c) {
            const float4 f = *(const float4*)(rp + (c << 8));
            r[4 * c + 0] += sgn * (double)f.x;
            r[4 * c + 1] += sgn * (double)f.y;
            r[4 * c + 2] += sgn * (double)f.z;
            r[4 * c + 3] += sgn * (double)f.w;
        }
    } else {
#pragma unroll
        for (int s = 0; s < 16; ++s) {
            int j = ((s >> 2) << 8) | (lane << 2) | (s & 3);
            r[s] += sgn * (double)w[(size_t)j * IN_F + i];
        }
    }
}

template <bool USE_T>
__global__ __launch_bounds__(64, 4) void bmp_kernel(const float* __restrict__ x,
                                                    const float* __restrict__ w,
                                                    const float* __restrict__ wT,
                                                    float* __restrict__ out, int rows) {
    __shared__ unsigned short act[IN_F + 8];
    const int lane = threadIdx.x;
    const int row = blockIdx.x;
    if (row >= rows) return;

    // ---- compacted active list of x row (binary SDR, ~51 of 512) ----
    const float* xrow = x + (size_t)row * IN_F;
    int cnt = 0;
#pragma unroll
    for (int c = 0; c < IN_F / 64; ++c) {
        bool pbit = xrow[c * 64 + lane] != 0.0f;
        unsigned long long m = __ballot(pbit);
        int pre = __popcll(m & ((1ull << lane) - 1ull));
        if (pbit) act[cnt + pre] = (unsigned short)(c * 64 + lane);
        cnt += __popcll(m);
    }
    __syncthreads();

    // ---- r = 2 * x @ wT  (fp64, registers; r is maintained incrementally later) ----
    double r[16];
#pragma unroll
    for (int s = 0; s < 16; ++s) r[s] = 0.0;
    {
        int iu = act[0];
        for (int k = 0; k < cnt; ++k) {
            int inx = act[k + 1];  // prefetch next index (act oversized; value unused at tail)
            wt_row_axpy<USE_T>(r, wT, w, iu, 1.0, lane);
            iu = inx;
        }
    }
#pragma unroll
    for (int s = 0; s < 16; ++s) r[s] *= 2.0;

    double vd[8];  // v = encoded @ W, slot p=4c+e <-> i = c*256 + lane*4 + e
#pragma unroll
    for (int p = 0; p < 8; ++p) vd[p] = 0.0;
    unsigned long long vkey[8];
#pragma unroll
    for (int p = 0; p < 8; ++p) vkey[p] = 0;

    unsigned enc = 0;  // per-lane 16-bit slot mask over OUT slots
    int O0 = -1, O1 = -1, O2 = -1, O3 = -1, O4 = -1, O5 = -1;  // previous xr set (uniform)

#pragma unroll 1
    for (int t = 0; t < K_ACTIVE; ++t) {
        // ---- argmax of residual over non-encoded j (lambd >> |dot| => exclusion) ----
        unsigned long long kb = 0;
#pragma unroll
        for (int s = 0; s < 16; ++s) {
            int j = ((s >> 2) << 8) | (lane << 2) | (s & 3);
            unsigned long long key = pack_key(r[s], 1023u ^ (unsigned)j, 1023ull);
            key = (enc & (1u << s)) ? 0ull : key;
            kb = key > kb ? key : kb;
        }
        const unsigned long long g = wave_max_u64(kb);
        const int bestj = 1023 ^ (int)(g & 1023ull);  // uniform (SGPR)
        if (lane == ((bestj >> 2) & 63))
            enc |= 1u << ((((bestj >> 8) & 3) << 2) | (bestj & 3));

        // ---- v += W[bestj][:]  (two 1KB-contiguous float4 loads) ----
        {
            const float* wr = w + ((size_t)bestj << 9) + (lane << 2);
#pragma unroll
            for (int c = 0; c < 2; ++c) {
                const float4 f = *(const float4*)(wr + (c << 8));
                vd[4 * c + 0] += (double)f.x;
                vd[4 * c + 1] += (double)f.y;
                vd[4 * c + 2] += (double)f.z;
                vd[4 * c + 3] += (double)f.w;
            }
        }

        // ---- kwta: top-6 of v via 6 packed-key DPP max-reductions ----
#pragma unroll
        for (int p = 0; p < 8; ++p) {
            int i = ((p >> 2) << 8) | (lane << 2) | (p & 3);
            vkey[p] = pack_key(vd[p], 511u ^ (unsigned)i, 511ull);
        }
        int N[6];
#pragma unroll
        for (int s2 = 0; s2 < K_IN; ++s2) {
            unsigned long long lk = vkey[0];
#pragma unroll
            for (int p = 1; p < 8; ++p) lk = vkey[p] > lk ? vkey[p] : lk;
            const unsigned long long gk = wave_max_u64(lk);
            N[s2] = 511 ^ (int)(gk & 511ull);  // uniform
#pragma unroll
            for (int p = 0; p < 8; ++p) vkey[p] = (vkey[p] == gk) ? 0ull : vkey[p];
        }

        // ---- incremental residual update: r -= (added rows) + (removed rows) ----
        if (t == 0) {
#pragma unroll
            for (int b = 0; b < 6; ++b) wt_row_axpy<USE_T>(r, wT, w, N[b], -1.0, lane);
        } else if (t < K_ACTIVE - 1) {
#pragma unroll
            for (int a = 0; a < 6; ++a) {
                const int o = (a == 0) ? O0 : (a == 1) ? O1 : (a == 2) ? O2
                              : (a == 3) ? O3 : (a == 4) ? O4 : O5;
                const bool stay = (o == N[0]) | (o == N[1]) | (o == N[2]) |
                                  (o == N[3]) | (o == N[4]) | (o == N[5]);
                if (!stay) wt_row_axpy<USE_T>(r, wT, w, o, 1.0, lane);
            }
#pragma unroll
            for (int b = 0; b < 6; ++b) {
                const int n = N[b];
                const bool was = (n == O0) | (n == O1) | (n == O2) |
                                 (n == O3) | (n == O4) | (n == O5);
                if (!was) wt_row_axpy<USE_T>(r, wT, w, n, -1.0, lane);
            }
        }
        O0 = N[0]; O1 = N[1]; O2 = N[2]; O3 = N[3]; O4 = N[4]; O5 = N[5];
    }

    // ---- outputs: encoded [rows][OUT_F] then xr [rows][IN_F], coalesced float4 ----
    float* oe = out + (size_t)row * OUT_F + (lane << 2);
#pragma unroll
    for (int c = 0; c < 4; ++c) {
        float4 v;
        v.x = (enc & (1u << (4 * c + 0))) ? 1.0f : 0.0f;
        v.y = (enc & (1u << (4 * c + 1))) ? 1.0f : 0.0f;
        v.z = (enc & (1u << (4 * c + 2))) ? 1.0f : 0.0f;
        v.w = (enc & (1u << (4 * c + 3))) ? 1.0f : 0.0f;
        *(float4*)(oe + (c << 8)) = v;
    }
    float* ox = out + (size_t)rows * OUT_F + (size_t)row * IN_F + (lane << 2);
#pragma unroll
    for (int c = 0; c < 2; ++c) {
        float4 v;  // selected slots are exactly the zeroed vkeys of the final step
        v.x = (vkey[4 * c + 0] == 0ull) ? 1.0f : 0.0f;
        v.y = (vkey[4 * c + 1] == 0ull) ? 1.0f : 0.0f;
        v.z = (vkey[4 * c + 2] == 0ull) ? 1.0f : 0.0f;
        v.w = (vkey[4 * c + 3] == 0ull) ? 1.0f : 0.0f;
        *(float4*)(ox + (c << 8)) = v;
    }
}

extern "C" void kernel_launch(void* const* d_in, const int* in_sizes, int n_in,
                              void* d_out, int out_size, void* d_ws, size_t ws_size,
                              hipStream_t stream) {
    const float* x = (const float*)d_in[0];
    const float* w = (const float*)d_in[1];
    float* out = (float*)d_out;
    const int rows = in_sizes[0] / IN_F;  // 4096

    const size_t wt_bytes = (size_t)IN_F * OUT_F * sizeof(float);
    if (ws_size >= wt_bytes && d_ws != nullptr) {
        float* wT = (float*)d_ws;
        transpose_w_kernel<<<dim3(IN_F / 32, OUT_F / 32), 256, 0, stream>>>(w, wT);
        bmp_kernel<true><<<rows, 64, 0, stream>>>(x, w, wT, out, rows);
    } else {
        bmp_kernel<false><<<rows, 64, 0, stream>>>(x, w, nullptr, out, rows);
    }
}

// Round 4
// 168.632 us; speedup vs baseline: 1.7477x; 1.1322x over previous
//
#include <hip/hip_runtime.h>

#define IN_F 512
#define OUT_F 1024
#define K_ACTIVE 11  // ceil(0.01 * 1024) serial MP steps
#define K_IN 6       // ceil(0.01 * 512) kwta winners

// 32x32 LDS-tiled transpose: w [OUT_F][IN_F] -> wT [IN_F][OUT_F]
__global__ __launch_bounds__(256) void transpose_w_kernel(const float* __restrict__ w,
                                                          float* __restrict__ wT) {
    __shared__ float tile[32][33];
    const int tx = threadIdx.x & 31;
    const int ty = threadIdx.x >> 5;  // 0..7
    const int i0 = blockIdx.x * 32;   // IN_F tile base
    const int j0 = blockIdx.y * 32;   // OUT_F tile base
#pragma unroll
    for (int k = 0; k < 4; ++k)
        tile[ty + 8 * k][tx] = w[(size_t)(j0 + ty + 8 * k) * IN_F + (i0 + tx)];
    __syncthreads();
#pragma unroll
    for (int k = 0; k < 4; ++k)
        wT[(size_t)(i0 + ty + 8 * k) * OUT_F + (j0 + tx)] = tile[tx][ty + 8 * k];
}

// ---- order-preserving fp64 -> u64 key, low bits carry reversed index ----
// max(key) == max value; ties -> lowest index. Drops 10 mantissa bits (2^-42 rel).
__device__ __forceinline__ unsigned long long pack_key(double v, unsigned rev,
                                                       unsigned long long mask) {
    unsigned long long b = (unsigned long long)__double_as_longlong(v);
    unsigned long long m =
        (unsigned long long)((long long)b >> 63) | 0x8000000000000000ull;
    unsigned long long u = b ^ m;  // monotonic total order
    return (u & ~mask) | (unsigned long long)rev;
}

// ---- wave-wide u64 max via DPP (VALU-speed, no LDS): result uniform ----
template <int C>
__device__ __forceinline__ unsigned long long dppmax(unsigned long long k) {
    unsigned lo = (unsigned)__builtin_amdgcn_update_dpp(0, (int)(unsigned)k, C, 0xF, 0xF, true);
    unsigned hi = (unsigned)__builtin_amdgcn_update_dpp(0, (int)(unsigned)(k >> 32), C, 0xF, 0xF, true);
    unsigned long long o = ((unsigned long long)hi << 32) | lo;
    return o > k ? o : k;
}

__device__ __forceinline__ unsigned long long wave_max_u64(unsigned long long k) {
    k = dppmax<0x111>(k);  // row_shr:1
    k = dppmax<0x112>(k);  // row_shr:2
    k = dppmax<0x114>(k);  // row_shr:4
    k = dppmax<0x118>(k);  // row_shr:8
    k = dppmax<0x142>(k);  // row_bcast:15
    k = dppmax<0x143>(k);  // row_bcast:31  -> lane 63 has wave max
    unsigned glo = (unsigned)__builtin_amdgcn_readlane((int)(unsigned)k, 63);
    unsigned ghi = (unsigned)__builtin_amdgcn_readlane((int)(unsigned)(k >> 32), 63);
    return ((unsigned long long)ghi << 32) | glo;
}

// r[s] += sgn * wT[i][slot s], slot s=4c+e <-> j = c*256 + lane*4 + e.
// USE_T path: 4 float4 loads, each 64 lanes x 16B = 1KB contiguous (coalesced).
template <bool USE_T>
__device__ __forceinline__ void wt_row_axpy(double* r, const float* __restrict__ wT,
                                            const float* __restrict__ w, int i,
                                            double sgn, int lane) {
    if constexpr (USE_T) {
        const float* rp = wT + ((size_t)i << 10) + (lane << 2);
#pragma unroll
        for (int c = 0; c < 4; ++c) {
            const float4 f = *(const float4*)(rp + (c << 8));
            r[4 * c + 0] += sgn * (double)f.x;
            r[4 * c + 1] += sgn * (double)f.y;
            r[4 * c + 2] += sgn * (double)f.z;
            r[4 * c + 3] += sgn * (double)f.w;
        }
    } else {
#pragma unroll
        for (int s = 0; s < 16; ++s) {
            int j = ((s >> 2) << 8) | (lane << 2) | (s & 3);
            r[s] += sgn * (double)w[(size_t)j * IN_F + i];
        }
    }
}

template <bool USE_T>
__global__ __launch_bounds__(64)
__attribute__((amdgpu_waves_per_eu(4, 4)))  // pin 4 waves/EU: 128-VGPR budget, no
                                            // spill-for-occupancy (R3: 300MB scratch)
void bmp_kernel(const float* __restrict__ x, const float* __restrict__ w,
                const float* __restrict__ wT, float* __restrict__ out, int rows) {
    __shared__ unsigned short act[IN_F + 8];
    const int lane = threadIdx.x;
    const int row = blockIdx.x;
    if (row >= rows) return;

    // ---- compacted active list of x row (binary SDR, ~51 of 512) ----
    const float* xrow = x + (size_t)row * IN_F;
    int cnt = 0;
#pragma unroll
    for (int c = 0; c < IN_F / 64; ++c) {
        bool pbit = xrow[c * 64 + lane] != 0.0f;
        unsigned long long m = __ballot(pbit);
        int pre = __popcll(m & ((1ull << lane) - 1ull));
        if (pbit) act[cnt + pre] = (unsigned short)(c * 64 + lane);
        cnt += __popcll(m);
    }
    __syncthreads();

    // ---- r = 2 * x @ wT  (fp64, registers; maintained incrementally later) ----
    double r[16];
#pragma unroll
    for (int s = 0; s < 16; ++s) r[s] = 0.0;
    {
        int iu = act[0];
#pragma unroll 1
        for (int k = 0; k < cnt; ++k) {
            int inx = act[k + 1];  // prefetch next index (act oversized)
            wt_row_axpy<USE_T>(r, wT, w, iu, 1.0, lane);
            iu = inx;
        }
    }
#pragma unroll
    for (int s = 0; s < 16; ++s) r[s] *= 2.0;

    double vd[8];  // v = encoded @ W, slot p=4c+e <-> i = c*256 + lane*4 + e
#pragma unroll
    for (int p = 0; p < 8; ++p) vd[p] = 0.0;

    unsigned enc = 0;      // per-lane 16-bit slot mask over OUT slots
    unsigned selmask = 0;  // per-lane 8-bit mask of final xr slots
    int O0 = -1, O1 = -1, O2 = -1, O3 = -1, O4 = -1, O5 = -1;  // xr set (uniform)

#pragma unroll 1
    for (int t = 0; t < K_ACTIVE; ++t) {
        // ---- argmax of residual over non-encoded j (lambd >> |dot| => exclusion) ----
        unsigned long long kb = 0;
#pragma unroll
        for (int s = 0; s < 16; ++s) {
            int j = ((s >> 2) << 8) | (lane << 2) | (s & 3);
            unsigned long long key = pack_key(r[s], 1023u ^ (unsigned)j, 1023ull);
            key = (enc & (1u << s)) ? 0ull : key;
            kb = key > kb ? key : kb;
        }
        const unsigned long long g = wave_max_u64(kb);
        const int bestj = 1023 ^ (int)(g & 1023ull);  // uniform (SGPR)
        if (lane == ((bestj >> 2) & 63))
            enc |= 1u << ((((bestj >> 8) & 3) << 2) | (bestj & 3));

        // ---- v += W[bestj][:]  (two 1KB-contiguous float4 loads) ----
        {
            const float* wr = w + ((size_t)bestj << 9) + (lane << 2);
#pragma unroll
            for (int c = 0; c < 2; ++c) {
                const float4 f = *(const float4*)(wr + (c << 8));
                vd[4 * c + 0] += (double)f.x;
                vd[4 * c + 1] += (double)f.y;
                vd[4 * c + 2] += (double)f.z;
                vd[4 * c + 3] += (double)f.w;
            }
        }

        // ---- kwta: top-6 of v via 6 packed-key DPP max-reductions ----
        int N[6];
        {
            unsigned long long vkey[8];  // transient: dies at end of this block
#pragma unroll
            for (int p = 0; p < 8; ++p) {
                int i = ((p >> 2) << 8) | (lane << 2) | (p & 3);
                vkey[p] = pack_key(vd[p], 511u ^ (unsigned)i, 511ull);
            }
#pragma unroll
            for (int s2 = 0; s2 < K_IN; ++s2) {
                unsigned long long lk = vkey[0];
#pragma unroll
                for (int p = 1; p < 8; ++p) lk = vkey[p] > lk ? vkey[p] : lk;
                const unsigned long long gk = wave_max_u64(lk);
                N[s2] = 511 ^ (int)(gk & 511ull);  // uniform
#pragma unroll
                for (int p = 0; p < 8; ++p) vkey[p] = (vkey[p] == gk) ? 0ull : vkey[p];
            }
            if (t == K_ACTIVE - 1) {
                selmask = 0;
#pragma unroll
                for (int p = 0; p < 8; ++p) selmask |= (vkey[p] == 0ull) ? (1u << p) : 0u;
            }
        }

        // ---- incremental residual update: r -= (added rows) + (removed rows) ----
        if (t == 0) {
#pragma unroll
            for (int b = 0; b < 6; ++b) wt_row_axpy<USE_T>(r, wT, w, N[b], -1.0, lane);
        } else if (t < K_ACTIVE - 1) {
#pragma unroll
            for (int a = 0; a < 6; ++a) {
                const int o = (a == 0) ? O0 : (a == 1) ? O1 : (a == 2) ? O2
                              : (a == 3) ? O3 : (a == 4) ? O4 : O5;
                const bool stay = (o == N[0]) | (o == N[1]) | (o == N[2]) |
                                  (o == N[3]) | (o == N[4]) | (o == N[5]);
                if (!stay) wt_row_axpy<USE_T>(r, wT, w, o, 1.0, lane);
            }
#pragma unroll
            for (int b = 0; b < 6; ++b) {
                const int n = N[b];
                const bool was = (n == O0) | (n == O1) | (n == O2) |
                                 (n == O3) | (n == O4) | (n == O5);
                if (!was) wt_row_axpy<USE_T>(r, wT, w, n, -1.0, lane);
            }
        }
        O0 = N[0]; O1 = N[1]; O2 = N[2]; O3 = N[3]; O4 = N[4]; O5 = N[5];
    }

    // ---- outputs: encoded [rows][OUT_F] then xr [rows][IN_F], coalesced float4 ----
    float* oe = out + (size_t)row * OUT_F + (lane << 2);
#pragma unroll
    for (int c = 0; c < 4; ++c) {
        float4 v;
        v.x = (enc & (1u << (4 * c + 0))) ? 1.0f : 0.0f;
        v.y = (enc & (1u << (4 * c + 1))) ? 1.0f : 0.0f;
        v.z = (enc & (1u << (4 * c + 2))) ? 1.0f : 0.0f;
        v.w = (enc & (1u << (4 * c + 3))) ? 1.0f : 0.0f;
        *(float4*)(oe + (c << 8)) = v;
    }
    float* ox = out + (size_t)rows * OUT_F + (size_t)row * IN_F + (lane << 2);
#pragma unroll
    for (int c = 0; c < 2; ++c) {
        float4 v;
        v.x = (selmask & (1u << (4 * c + 0))) ? 1.0f : 0.0f;
        v.y = (selmask & (1u << (4 * c + 1))) ? 1.0f : 0.0f;
        v.z = (selmask & (1u << (4 * c + 2))) ? 1.0f : 0.0f;
        v.w = (selmask & (1u << (4 * c + 3))) ? 1.0f : 0.0f;
        *(float4*)(ox + (c << 8)) = v;
    }
}

extern "C" void kernel_launch(void* const* d_in, const int* in_sizes, int n_in,
                              void* d_out, int out_size, void* d_ws, size_t ws_size,
                              hipStream_t stream) {
    const float* x = (const float*)d_in[0];
    const float* w = (const float*)d_in[1];
    float* out = (float*)d_out;
    const int rows = in_sizes[0] / IN_F;  // 4096

    const size_t wt_bytes = (size_t)IN_F * OUT_F * sizeof(float);
    if (ws_size >= wt_bytes && d_ws != nullptr) {
        float* wT = (float*)d_ws;
        transpose_w_kernel<<<dim3(IN_F / 32, OUT_F / 32), 256, 0, stream>>>(w, wT);
        bmp_kernel<true><<<rows, 64, 0, stream>>>(x, w, wT, out, rows);
    } else {
        bmp_kernel<false><<<rows, 64, 0, stream>>>(x, w, nullptr, out, rows);
    }
}